// Round 1
// baseline (1651.581 us; speedup 1.0000x reference)
//
#include <hip/hip_runtime.h>

#define NN 100000
#define NE 800000

// deg[i] = 1.0 (self loop)
extern "C" __global__ void k_deg_init(float* __restrict__ deg) {
    int i = blockIdx.x * 256 + threadIdx.x;
    if (i < NN) deg[i] = 1.0f;
}

// deg[dst] += 1 per edge
extern "C" __global__ void k_deg_count(const int* __restrict__ dst, float* __restrict__ deg) {
    int e = blockIdx.x * 256 + threadIdx.x;
    if (e < NE) atomicAdd(&deg[dst[e]], 1.0f);
}

extern "C" __global__ void k_dinv(const float* __restrict__ deg, float* __restrict__ dinv) {
    int i = blockIdx.x * 256 + threadIdx.x;
    if (i < NN) dinv[i] = rsqrtf(deg[i]);
}

// agg[i][:] = x[i][:] * dinv[i]^2   (self-loop term; also initializes the 0xAA-poisoned d_out)
extern "C" __global__ void k_agg_init(const float4* __restrict__ x4,
                                      const float* __restrict__ dinv,
                                      float4* __restrict__ agg4) {
    int i = blockIdx.x * 256 + threadIdx.x;   // over NN*32 float4's (exact)
    int row = i >> 5;                          // 32 float4 per 128-ch row
    float s = dinv[row];
    s *= s;
    float4 v = x4[i];
    v.x *= s; v.y *= s; v.z *= s; v.w *= s;
    agg4[i] = v;
}

// 32 lanes per edge, one float4 per lane, 4 f32 atomics per lane
extern "C" __global__ void k_scatter(const int* __restrict__ src, const int* __restrict__ dst,
                                     const float* __restrict__ dinv,
                                     const float4* __restrict__ x4,
                                     float* __restrict__ agg) {
    int t = blockIdx.x * 256 + threadIdx.x;
    int e = t >> 5;
    if (e >= NE) return;
    int j = t & 31;
    int s = src[e], d = dst[e];
    float nrm = dinv[s] * dinv[d];
    float4 v = x4[s * 32 + j];
    float* p = agg + (size_t)d * 128 + j * 4;
    atomicAdd(p + 0, v.x * nrm);
    atomicAdd(p + 1, v.y * nrm);
    atomicAdd(p + 2, v.z * nrm);
    atomicAdd(p + 3, v.w * nrm);
}

// In-place h = agg @ W + bias. W (128x128 f32 = 64KB) in LDS.
// Each row owned by one half-wave (32 lanes x 4 cols); stores are program-ordered
// after all reads of that row within the same wave -> in-place is race-free.
extern "C" __global__ void __launch_bounds__(256) k_gemm(float* __restrict__ agg,
                                                         const float* __restrict__ W,
                                                         const float* __restrict__ bias) {
    __shared__ float Ws[128 * 128];
    for (int i = threadIdx.x; i < 128 * 32; i += 256)
        ((float4*)Ws)[i] = ((const float4*)W)[i];
    __syncthreads();

    int lane = threadIdx.x & 31;
    int row  = blockIdx.x * 8 + (threadIdx.x >> 5);   // 12500 blocks * 8 rows = NN exact
    float* arow = agg + (size_t)row * 128;
    int c0 = lane * 4;

    float4 b = *(const float4*)(bias + c0);
    float a0 = b.x, a1 = b.y, a2 = b.z, a3 = b.w;

#pragma unroll 8
    for (int k = 0; k < 128; k++) {
        float a = arow[k];                              // broadcast load (same addr across 32 lanes)
        float4 w = *(const float4*)(Ws + k * 128 + c0); // ds_read_b128
        a0 += a * w.x; a1 += a * w.y; a2 += a * w.z; a3 += a * w.w;
    }

    float4 o; o.x = a0; o.y = a1; o.z = a2; o.w = a3;
    *(float4*)(arow + c0) = o;
}

extern "C" void kernel_launch(void* const* d_in, const int* in_sizes, int n_in,
                              void* d_out, int out_size, void* d_ws, size_t ws_size,
                              hipStream_t stream) {
    const float* x    = (const float*)d_in[0];
    const int*   ei   = (const int*)d_in[1];   // (2, NE) row-major int32
    const float* W    = (const float*)d_in[2]; // (128,128) row-major
    const float* bias = (const float*)d_in[3];
    float* out = (float*)d_out;

    float* deg  = (float*)d_ws;       // NN floats
    float* dinv = deg + NN;           // NN floats

    const int* src = ei;
    const int* dst = ei + NE;

    k_deg_init <<<(NN + 255) / 256, 256, 0, stream>>>(deg);
    k_deg_count<<<(NE + 255) / 256, 256, 0, stream>>>(dst, deg);
    k_dinv     <<<(NN + 255) / 256, 256, 0, stream>>>(deg, dinv);
    k_agg_init <<<(NN * 128 / 4) / 256, 256, 0, stream>>>((const float4*)x, dinv, (float4*)out);
    k_scatter  <<<(NE * 32) / 256, 256, 0, stream>>>(src, dst, dinv, (const float4*)x, out);
    k_gemm     <<<NN / 8, 256, 0, stream>>>(out, W, bias);
}

// Round 5
// 441.222 us; speedup vs baseline: 3.7432x; 3.7432x over previous
//
#include <hip/hip_runtime.h>

#define NN 100000
#define NE 800000
#define NBLK_SCAN 98   // ceil(NN/1024)

// ---- CSR build ----------------------------------------------------------

// cnt[dst]++ per edge (int atomics)
extern "C" __global__ void k_count(const int* __restrict__ dst, int* __restrict__ cnt) {
    int e = blockIdx.x * 256 + threadIdx.x;
    if (e < NE) atomicAdd(&cnt[dst[e]], 1);
}

// block-level exclusive scan: 1024 elems/block (256 thr x 4), writes partial
// exclusive scan to row_ptr and per-block total to bsum
extern "C" __global__ void k_scan1(const int* __restrict__ cnt, int* __restrict__ row_ptr,
                                   int* __restrict__ bsum) {
    __shared__ int sh[256];
    int t = threadIdx.x;
    int base = blockIdx.x * 1024 + t * 4;
    int v0 = (base + 0 < NN) ? cnt[base + 0] : 0;
    int v1 = (base + 1 < NN) ? cnt[base + 1] : 0;
    int v2 = (base + 2 < NN) ? cnt[base + 2] : 0;
    int v3 = (base + 3 < NN) ? cnt[base + 3] : 0;
    int tsum = v0 + v1 + v2 + v3;
    sh[t] = tsum;
    __syncthreads();
    int x = tsum;
    for (int off = 1; off < 256; off <<= 1) {
        int y = (t >= off) ? sh[t - off] : 0;
        __syncthreads();
        x += y;
        sh[t] = x;
        __syncthreads();
    }
    int ex = x - tsum;
    if (t == 255) bsum[blockIdx.x] = x;
    if (base + 0 < NN) row_ptr[base + 0] = ex;
    if (base + 1 < NN) row_ptr[base + 1] = ex + v0;
    if (base + 2 < NN) row_ptr[base + 2] = ex + v0 + v1;
    if (base + 3 < NN) row_ptr[base + 3] = ex + v0 + v1 + v2;
}

// scan the 98 block sums (1 block, 128 threads)
extern "C" __global__ void k_scan2(int* __restrict__ bsum) {
    __shared__ int sh[128];
    int t = threadIdx.x;
    int v = (t < NBLK_SCAN) ? bsum[t] : 0;
    sh[t] = v;
    __syncthreads();
    int x = v;
    for (int off = 1; off < 128; off <<= 1) {
        int y = (t >= off) ? sh[t - off] : 0;
        __syncthreads();
        x += y;
        sh[t] = x;
        __syncthreads();
    }
    if (t < NBLK_SCAN) bsum[t] = x - v;
}

// add scanned block offsets
extern "C" __global__ void k_scan3(int* __restrict__ row_ptr, const int* __restrict__ bsum) {
    int i = blockIdx.x * 256 + threadIdx.x;
    if (i < NN) row_ptr[i] += bsum[i >> 10];
}

extern "C" __global__ void k_dinv(const int* __restrict__ cnt, float* __restrict__ dinv) {
    int i = blockIdx.x * 256 + threadIdx.x;
    if (i < NN) dinv[i] = rsqrtf(1.0f + (float)cnt[i]);
}

// bucket[row_ptr[d] + cursor[d]++] = src
extern "C" __global__ void k_bucket(const int* __restrict__ src, const int* __restrict__ dst,
                                    const int* __restrict__ row_ptr, int* __restrict__ cursor,
                                    int* __restrict__ bucket) {
    int e = blockIdx.x * 256 + threadIdx.x;
    if (e >= NE) return;
    int d = dst[e];
    int pos = row_ptr[d] + atomicAdd(&cursor[d], 1);
    bucket[pos] = src[e];
}

// ---- aggregate (gather) -------------------------------------------------
// one wave (64 lanes x float2) per node; x rows are L3-resident (51.2 MB)
extern "C" __global__ void __launch_bounds__(256) k_gather(
        const float2* __restrict__ x2, const float* __restrict__ dinv,
        const int* __restrict__ row_ptr, const int* __restrict__ cnt,
        const int* __restrict__ bucket, float2* __restrict__ out2) {
    int t = blockIdx.x * 256 + threadIdx.x;
    int node = t >> 6;
    int lane = t & 63;
    float di = dinv[node];
    float2 acc = x2[(size_t)node * 64 + lane];
    float s2 = di * di;
    acc.x *= s2; acc.y *= s2;
    int start = row_ptr[node];
    int len   = cnt[node];
    for (int j = 0; j < len; j++) {
        int s = bucket[start + j];
        float nrm = dinv[s] * di;
        float2 v = x2[(size_t)s * 64 + lane];
        acc.x += v.x * nrm;
        acc.y += v.y * nrm;
    }
    out2[(size_t)node * 64 + lane] = acc;
}

// ---- dense transform (in-place), unchanged from round 1 -----------------
extern "C" __global__ void __launch_bounds__(256) k_gemm(float* __restrict__ agg,
                                                         const float* __restrict__ W,
                                                         const float* __restrict__ bias) {
    __shared__ float Ws[128 * 128];
    for (int i = threadIdx.x; i < 128 * 32; i += 256)
        ((float4*)Ws)[i] = ((const float4*)W)[i];
    __syncthreads();

    int lane = threadIdx.x & 31;
    int row  = blockIdx.x * 8 + (threadIdx.x >> 5);
    float* arow = agg + (size_t)row * 128;
    int c0 = lane * 4;

    float4 b = *(const float4*)(bias + c0);
    float a0 = b.x, a1 = b.y, a2 = b.z, a3 = b.w;

#pragma unroll 8
    for (int k = 0; k < 128; k++) {
        float a = arow[k];
        float4 w = *(const float4*)(Ws + k * 128 + c0);
        a0 += a * w.x; a1 += a * w.y; a2 += a * w.z; a3 += a * w.w;
    }

    float4 o; o.x = a0; o.y = a1; o.z = a2; o.w = a3;
    *(float4*)(arow + c0) = o;
}

extern "C" void kernel_launch(void* const* d_in, const int* in_sizes, int n_in,
                              void* d_out, int out_size, void* d_ws, size_t ws_size,
                              hipStream_t stream) {
    const float* x    = (const float*)d_in[0];
    const int*   ei   = (const int*)d_in[1];
    const float* W    = (const float*)d_in[2];
    const float* bias = (const float*)d_in[3];
    float* out = (float*)d_out;

    const int* src = ei;
    const int* dst = ei + NE;

    // workspace layout (all 4-byte elems)
    int*   cnt     = (int*)d_ws;           // NN
    int*   cursor  = cnt + NN;             // NN  (zeroed together with cnt)
    int*   row_ptr = cursor + NN;          // NN
    float* dinv    = (float*)(row_ptr + NN); // NN
    int*   bsum    = (int*)(dinv + NN);    // 128
    int*   bucket  = bsum + 128;           // NE

    hipMemsetAsync(d_ws, 0, (size_t)2 * NN * sizeof(int), stream);

    k_count <<<(NE + 255) / 256, 256, 0, stream>>>(dst, cnt);
    k_scan1 <<<NBLK_SCAN, 256, 0, stream>>>(cnt, row_ptr, bsum);
    k_scan2 <<<1, 128, 0, stream>>>(bsum);
    k_scan3 <<<(NN + 255) / 256, 256, 0, stream>>>(row_ptr, bsum);
    k_dinv  <<<(NN + 255) / 256, 256, 0, stream>>>(cnt, dinv);
    k_bucket<<<(NE + 255) / 256, 256, 0, stream>>>(src, dst, row_ptr, cursor, bucket);
    k_gather<<<NN * 64 / 256, 256, 0, stream>>>((const float2*)x, dinv, row_ptr, cnt,
                                                bucket, (float2*)out);
    k_gemm  <<<NN / 8, 256, 0, stream>>>(out, W, bias);
}

// Round 6
// 320.238 us; speedup vs baseline: 5.1574x; 1.3778x over previous
//
#include <hip/hip_runtime.h>

#define NN 100000
#define NE 800000
#define NBLK_SCAN 98   // ceil(NN/1024)

// ---- CSR build ----------------------------------------------------------

extern "C" __global__ void k_count(const int* __restrict__ dst, int* __restrict__ cnt) {
    int e = blockIdx.x * 256 + threadIdx.x;
    if (e < NE) atomicAdd(&cnt[dst[e]], 1);
}

extern "C" __global__ void k_scan1(const int* __restrict__ cnt, int* __restrict__ row_ptr,
                                   int* __restrict__ bsum) {
    __shared__ int sh[256];
    int t = threadIdx.x;
    int base = blockIdx.x * 1024 + t * 4;
    int v0 = (base + 0 < NN) ? cnt[base + 0] : 0;
    int v1 = (base + 1 < NN) ? cnt[base + 1] : 0;
    int v2 = (base + 2 < NN) ? cnt[base + 2] : 0;
    int v3 = (base + 3 < NN) ? cnt[base + 3] : 0;
    int tsum = v0 + v1 + v2 + v3;
    sh[t] = tsum;
    __syncthreads();
    int x = tsum;
    for (int off = 1; off < 256; off <<= 1) {
        int y = (t >= off) ? sh[t - off] : 0;
        __syncthreads();
        x += y;
        sh[t] = x;
        __syncthreads();
    }
    int ex = x - tsum;
    if (t == 255) bsum[blockIdx.x] = x;
    if (base + 0 < NN) row_ptr[base + 0] = ex;
    if (base + 1 < NN) row_ptr[base + 1] = ex + v0;
    if (base + 2 < NN) row_ptr[base + 2] = ex + v0 + v1;
    if (base + 3 < NN) row_ptr[base + 3] = ex + v0 + v1 + v2;
}

extern "C" __global__ void k_scan2(int* __restrict__ bsum) {
    __shared__ int sh[128];
    int t = threadIdx.x;
    int v = (t < NBLK_SCAN) ? bsum[t] : 0;
    sh[t] = v;
    __syncthreads();
    int x = v;
    for (int off = 1; off < 128; off <<= 1) {
        int y = (t >= off) ? sh[t - off] : 0;
        __syncthreads();
        x += y;
        sh[t] = x;
        __syncthreads();
    }
    if (t < NBLK_SCAN) bsum[t] = x - v;
}

extern "C" __global__ void k_scan3(int* __restrict__ row_ptr, const int* __restrict__ bsum) {
    int i = blockIdx.x * 256 + threadIdx.x;
    if (i < NN) row_ptr[i] += bsum[i >> 10];
}

extern "C" __global__ void k_dinv(const int* __restrict__ cnt, float* __restrict__ dinv) {
    int i = blockIdx.x * 256 + threadIdx.x;
    if (i < NN) dinv[i] = rsqrtf(1.0f + (float)cnt[i]);
}

extern "C" __global__ void k_bucket(const int* __restrict__ src, const int* __restrict__ dst,
                                    const int* __restrict__ row_ptr, int* __restrict__ cursor,
                                    int* __restrict__ bucket) {
    int e = blockIdx.x * 256 + threadIdx.x;
    if (e >= NE) return;
    int d = dst[e];
    int pos = row_ptr[d] + atomicAdd(&cursor[d], 1);
    bucket[pos] = src[e];
}

// ---- aggregate (gather) -------------------------------------------------
// one wave (64 lanes x float2) per node; x rows are L3-resident (51.2 MB).
// Edge loop unrolled x4 so 4 independent L3 row-loads are in flight.
extern "C" __global__ void __launch_bounds__(256) k_gather(
        const float2* __restrict__ x2, const float* __restrict__ dinv,
        const int* __restrict__ row_ptr, const int* __restrict__ cnt,
        const int* __restrict__ bucket, float2* __restrict__ out2) {
    int t = blockIdx.x * 256 + threadIdx.x;
    int node = t >> 6;
    int lane = t & 63;
    float di = dinv[node];
    float2 acc = x2[(size_t)node * 64 + lane];
    float s2 = di * di;
    acc.x *= s2; acc.y *= s2;
    int j   = row_ptr[node];
    int end = j + cnt[node];
    for (; j + 4 <= end; j += 4) {
        int s0 = bucket[j + 0];
        int s1 = bucket[j + 1];
        int s2i = bucket[j + 2];
        int s3 = bucket[j + 3];
        float n0 = dinv[s0] * di;
        float n1 = dinv[s1] * di;
        float n2 = dinv[s2i] * di;
        float n3 = dinv[s3] * di;
        float2 v0 = x2[(size_t)s0 * 64 + lane];
        float2 v1 = x2[(size_t)s1 * 64 + lane];
        float2 v2 = x2[(size_t)s2i * 64 + lane];
        float2 v3 = x2[(size_t)s3 * 64 + lane];
        acc.x += v0.x * n0 + v1.x * n1 + v2.x * n2 + v3.x * n3;
        acc.y += v0.y * n0 + v1.y * n1 + v2.y * n2 + v3.y * n3;
    }
    for (; j < end; j++) {
        int s = bucket[j];
        float nrm = dinv[s] * di;
        float2 v = x2[(size_t)s * 64 + lane];
        acc.x += v.x * nrm;
        acc.y += v.y * nrm;
    }
    out2[(size_t)node * 64 + lane] = acc;
}

// ---- dense transform (in-place), 8-row blocked --------------------------
// Each 32-lane group owns 8 FULL rows (no column split -> in-place is
// race-free: all reads of a row happen in this group's k-loop, all writes
// after). W ds_read_b128 amortized over 8 rows: LDS traffic /8 vs round 5.
extern "C" __global__ void __launch_bounds__(256) k_gemm(float* __restrict__ agg,
                                                         const float* __restrict__ W,
                                                         const float* __restrict__ bias) {
    __shared__ float Ws[128 * 128];
    for (int i = threadIdx.x; i < 128 * 32; i += 256)
        ((float4*)Ws)[i] = ((const float4*)W)[i];
    __syncthreads();

    int lane = threadIdx.x & 31;
    int grp  = threadIdx.x >> 5;
    long row0 = ((long)blockIdx.x * 8 + grp) * 8;   // 8 rows per 32-lane group
    if (row0 >= NN) return;                          // after the only __syncthreads
    int c0 = lane * 4;

    float* ar[8];
#pragma unroll
    for (int r = 0; r < 8; r++) ar[r] = agg + (row0 + r) * 128;

    float4 b = *(const float4*)(bias + c0);
    float acc[8][4];
#pragma unroll
    for (int r = 0; r < 8; r++) {
        acc[r][0] = b.x; acc[r][1] = b.y; acc[r][2] = b.z; acc[r][3] = b.w;
    }

    for (int k4 = 0; k4 < 32; k4++) {
        float4 w0 = *(const float4*)(Ws + (k4 * 4 + 0) * 128 + c0);
        float4 w1 = *(const float4*)(Ws + (k4 * 4 + 1) * 128 + c0);
        float4 w2 = *(const float4*)(Ws + (k4 * 4 + 2) * 128 + c0);
        float4 w3 = *(const float4*)(Ws + (k4 * 4 + 3) * 128 + c0);
#pragma unroll
        for (int r = 0; r < 8; r++) {
            float4 a = *(const float4*)(ar[r] + k4 * 4);   // group-broadcast, L1/L3
            acc[r][0] += a.x * w0.x + a.y * w1.x + a.z * w2.x + a.w * w3.x;
            acc[r][1] += a.x * w0.y + a.y * w1.y + a.z * w2.y + a.w * w3.y;
            acc[r][2] += a.x * w0.z + a.y * w1.z + a.z * w2.z + a.w * w3.z;
            acc[r][3] += a.x * w0.w + a.y * w1.w + a.z * w2.w + a.w * w3.w;
        }
    }

#pragma unroll
    for (int r = 0; r < 8; r++) {
        float4 o; o.x = acc[r][0]; o.y = acc[r][1]; o.z = acc[r][2]; o.w = acc[r][3];
        *(float4*)(ar[r] + c0) = o;
    }
}

extern "C" void kernel_launch(void* const* d_in, const int* in_sizes, int n_in,
                              void* d_out, int out_size, void* d_ws, size_t ws_size,
                              hipStream_t stream) {
    const float* x    = (const float*)d_in[0];
    const int*   ei   = (const int*)d_in[1];
    const float* W    = (const float*)d_in[2];
    const float* bias = (const float*)d_in[3];
    float* out = (float*)d_out;

    const int* src = ei;
    const int* dst = ei + NE;

    int*   cnt     = (int*)d_ws;             // NN
    int*   cursor  = cnt + NN;               // NN  (zeroed together with cnt)
    int*   row_ptr = cursor + NN;            // NN
    float* dinv    = (float*)(row_ptr + NN); // NN
    int*   bsum    = (int*)(dinv + NN);      // 128
    int*   bucket  = bsum + 128;             // NE

    hipMemsetAsync(d_ws, 0, (size_t)2 * NN * sizeof(int), stream);

    k_count <<<(NE + 255) / 256, 256, 0, stream>>>(dst, cnt);
    k_scan1 <<<NBLK_SCAN, 256, 0, stream>>>(cnt, row_ptr, bsum);
    k_scan2 <<<1, 128, 0, stream>>>(bsum);
    k_scan3 <<<(NN + 255) / 256, 256, 0, stream>>>(row_ptr, bsum);
    k_dinv  <<<(NN + 255) / 256, 256, 0, stream>>>(cnt, dinv);
    k_bucket<<<(NE + 255) / 256, 256, 0, stream>>>(src, dst, row_ptr, cursor, bucket);
    k_gather<<<NN * 64 / 256, 256, 0, stream>>>((const float2*)x, dinv, row_ptr, cnt,
                                                bucket, (float2*)out);
    k_gemm  <<<(12500 + 7) / 8, 256, 0, stream>>>(out, W, bias);
}

// Round 9
// 275.475 us; speedup vs baseline: 5.9954x; 1.1625x over previous
//
#include <hip/hip_runtime.h>

#define NN 100000
#define NE 800000
#define NBLK_SCAN 98   // ceil(NN/1024)

typedef __attribute__((ext_vector_type(8))) short bf16x8;
typedef __attribute__((ext_vector_type(4))) float f32x4;

static __device__ __forceinline__ unsigned short f2b(float f) {
    unsigned int u = __builtin_bit_cast(unsigned int, f);
    unsigned int r = (u + 0x7FFFu + ((u >> 16) & 1u)) >> 16;   // RNE
    return (unsigned short)r;
}

// ---- CSR build ----------------------------------------------------------

extern "C" __global__ void k_count(const int* __restrict__ dst, int* __restrict__ cnt) {
    int e = blockIdx.x * 256 + threadIdx.x;
    if (e < NE) atomicAdd(&cnt[dst[e]], 1);
}

extern "C" __global__ void k_scan1(const int* __restrict__ cnt, int* __restrict__ row_ptr,
                                   int* __restrict__ bsum) {
    __shared__ int sh[256];
    int t = threadIdx.x;
    int base = blockIdx.x * 1024 + t * 4;
    int v0 = (base + 0 < NN) ? cnt[base + 0] : 0;
    int v1 = (base + 1 < NN) ? cnt[base + 1] : 0;
    int v2 = (base + 2 < NN) ? cnt[base + 2] : 0;
    int v3 = (base + 3 < NN) ? cnt[base + 3] : 0;
    int tsum = v0 + v1 + v2 + v3;
    sh[t] = tsum;
    __syncthreads();
    int x = tsum;
    for (int off = 1; off < 256; off <<= 1) {
        int y = (t >= off) ? sh[t - off] : 0;
        __syncthreads();
        x += y;
        sh[t] = x;
        __syncthreads();
    }
    int ex = x - tsum;
    if (t == 255) bsum[blockIdx.x] = x;
    if (base + 0 < NN) row_ptr[base + 0] = ex;
    if (base + 1 < NN) row_ptr[base + 1] = ex + v0;
    if (base + 2 < NN) row_ptr[base + 2] = ex + v0 + v1;
    if (base + 3 < NN) row_ptr[base + 3] = ex + v0 + v1 + v2;
}

extern "C" __global__ void k_scan2(int* __restrict__ bsum) {
    __shared__ int sh[128];
    int t = threadIdx.x;
    int v = (t < NBLK_SCAN) ? bsum[t] : 0;
    sh[t] = v;
    __syncthreads();
    int x = v;
    for (int off = 1; off < 128; off <<= 1) {
        int y = (t >= off) ? sh[t - off] : 0;
        __syncthreads();
        x += y;
        sh[t] = x;
        __syncthreads();
    }
    if (t < NBLK_SCAN) bsum[t] = x - v;
}

extern "C" __global__ void k_scan3(int* __restrict__ row_ptr, const int* __restrict__ bsum) {
    int i = blockIdx.x * 256 + threadIdx.x;
    if (i < NN) row_ptr[i] += bsum[i >> 10];
}

extern "C" __global__ void k_dinv(const int* __restrict__ cnt, float* __restrict__ dinv) {
    int i = blockIdx.x * 256 + threadIdx.x;
    if (i < NN) dinv[i] = rsqrtf(1.0f + (float)cnt[i]);
}

extern "C" __global__ void k_bucket(const int* __restrict__ src, const int* __restrict__ dst,
                                    const int* __restrict__ row_ptr, int* __restrict__ cursor,
                                    int* __restrict__ bucket) {
    int e = blockIdx.x * 256 + threadIdx.x;
    if (e >= NE) return;
    int d = dst[e];
    int pos = row_ptr[d] + atomicAdd(&cursor[d], 1);
    bucket[pos] = src[e];
}

// ---- W^T -> bf16, pre-swizzled for conflict-free LDS b128 reads ---------
// u16 index = (n*128 + k) ^ ((n&7)<<3); bijective within each row's 128 elems.
extern "C" __global__ void k_wprep(const float* __restrict__ W, unsigned short* __restrict__ wt) {
    int i = blockIdx.x * 256 + threadIdx.x;   // i over 128x128, W row-major [k][n]
    if (i < 128 * 128) {
        int k = i >> 7, n = i & 127;
        int idx = (n * 128 + k) ^ ((n & 7) << 3);
        wt[idx] = f2b(W[i]);
    }
}

// ---- aggregate (gather) -------------------------------------------------
extern "C" __global__ void __launch_bounds__(256) k_gather(
        const float2* __restrict__ x2, const float* __restrict__ dinv,
        const int* __restrict__ row_ptr, const int* __restrict__ cnt,
        const int* __restrict__ bucket, float2* __restrict__ out2) {
    int t = blockIdx.x * 256 + threadIdx.x;
    int node = t >> 6;
    int lane = t & 63;
    float di = dinv[node];
    float2 acc = x2[(size_t)node * 64 + lane];
    float s2 = di * di;
    acc.x *= s2; acc.y *= s2;
    int j   = row_ptr[node];
    int end = j + cnt[node];
    for (; j + 4 <= end; j += 4) {
        int s0 = bucket[j + 0];
        int s1 = bucket[j + 1];
        int s2i = bucket[j + 2];
        int s3 = bucket[j + 3];
        float n0 = dinv[s0] * di;
        float n1 = dinv[s1] * di;
        float n2 = dinv[s2i] * di;
        float n3 = dinv[s3] * di;
        float2 v0 = x2[(size_t)s0 * 64 + lane];
        float2 v1 = x2[(size_t)s1 * 64 + lane];
        float2 v2 = x2[(size_t)s2i * 64 + lane];
        float2 v3 = x2[(size_t)s3 * 64 + lane];
        acc.x += v0.x * n0 + v1.x * n1 + v2.x * n2 + v3.x * n3;
        acc.y += v0.y * n0 + v1.y * n1 + v2.y * n2 + v3.y * n3;
    }
    for (; j < end; j++) {
        int s = bucket[j];
        float nrm = dinv[s] * di;
        float2 v = x2[(size_t)s * 64 + lane];
        acc.x += v.x * nrm;
        acc.y += v.y * nrm;
    }
    out2[(size_t)node * 64 + lane] = acc;
}

// ---- dense transform: bf16 MFMA, in-place on agg ------------------------
// Block = 4 waves x 32 rows = 128 rows. Per wave: 2 M-tiles x 8 N-tiles of
// mfma_f32_16x16x32_bf16, K-loop 4x32. A: f32 from agg (own rows only ->
// in-place race-free; tail reads clamped, stores guarded). B: bf16 W^T from
// LDS, XOR-swizzled (2-way banks only). C/D layout per m89: col=lane&15,
// row=(lane>>4)*4+reg.
extern "C" __global__ void __launch_bounds__(256) k_gemm(
        float* __restrict__ agg, const unsigned int* __restrict__ wt,
        const float* __restrict__ bias) {
    __shared__ unsigned int wt_lds[8192];   // 32 KB, already-swizzled Wt bf16
    for (int i = threadIdx.x; i < 8192; i += 256)
        wt_lds[i] = wt[i];
    __syncthreads();

    int lane = threadIdx.x & 63;
    int wave = threadIdx.x >> 6;
    int r16  = lane & 15;     // A row-in-tile / B+D col-in-tile
    int kg   = lane >> 4;     // k-group 0..3
    long m0  = (long)blockIdx.x * 128 + wave * 32;

    f32x4 acc[2][8];
#pragma unroll
    for (int nt = 0; nt < 8; nt++) {
        float bv = bias[nt * 16 + r16];
        f32x4 iv = {bv, bv, bv, bv};
        acc[0][nt] = iv;
        acc[1][nt] = iv;
    }

#pragma unroll
    for (int ks = 0; ks < 4; ks++) {
        bf16x8 afr[2];
#pragma unroll
        for (int mt = 0; mt < 2; mt++) {
            long r = m0 + mt * 16 + r16;
            if (r >= NN) r = NN - 1;                 // benign clamp; stores guarded
            const float* p = agg + r * 128 + ks * 32 + kg * 8;
            float4 fa = *(const float4*)p;
            float4 fb = *(const float4*)(p + 4);
            bf16x8 v;
            v[0] = (short)f2b(fa.x); v[1] = (short)f2b(fa.y);
            v[2] = (short)f2b(fa.z); v[3] = (short)f2b(fa.w);
            v[4] = (short)f2b(fb.x); v[5] = (short)f2b(fb.y);
            v[6] = (short)f2b(fb.z); v[7] = (short)f2b(fb.w);
            afr[mt] = v;
        }
#pragma unroll
        for (int nt = 0; nt < 8; nt++) {
            int row = nt * 16 + r16;
            int idx = (row * 128 + ks * 32 + kg * 8) ^ ((row & 7) << 3);
            bf16x8 bfr = *(const bf16x8*)((const short*)wt_lds + idx);
            acc[0][nt] = __builtin_amdgcn_mfma_f32_16x16x32_bf16(afr[0], bfr, acc[0][nt], 0, 0, 0);
            acc[1][nt] = __builtin_amdgcn_mfma_f32_16x16x32_bf16(afr[1], bfr, acc[1][nt], 0, 0, 0);
        }
    }

#pragma unroll
    for (int mt = 0; mt < 2; mt++) {
#pragma unroll
        for (int j = 0; j < 4; j++) {
            long r = m0 + mt * 16 + kg * 4 + j;
            if (r < NN) {
#pragma unroll
                for (int nt = 0; nt < 8; nt++)
                    agg[r * 128 + nt * 16 + r16] = acc[mt][nt][j];
            }
        }
    }
}

extern "C" void kernel_launch(void* const* d_in, const int* in_sizes, int n_in,
                              void* d_out, int out_size, void* d_ws, size_t ws_size,
                              hipStream_t stream) {
    const float* x    = (const float*)d_in[0];
    const int*   ei   = (const int*)d_in[1];
    const float* W    = (const float*)d_in[2];
    const float* bias = (const float*)d_in[3];
    float* out = (float*)d_out;

    const int* src = ei;
    const int* dst = ei + NE;

    int*   cnt     = (int*)d_ws;             // NN
    int*   cursor  = cnt + NN;               // NN  (zeroed together with cnt)
    int*   row_ptr = cursor + NN;            // NN
    float* dinv    = (float*)(row_ptr + NN); // NN
    int*   bsum    = (int*)(dinv + NN);      // 128
    int*   bucket  = bsum + 128;             // NE
    unsigned int* wt = (unsigned int*)(bucket + NE); // 8192 u32 = 32 KB (bf16 Wt, swizzled)

    hipMemsetAsync(d_ws, 0, (size_t)2 * NN * sizeof(int), stream);

    k_wprep <<<64, 256, 0, stream>>>(W, (unsigned short*)wt);
    k_count <<<(NE + 255) / 256, 256, 0, stream>>>(dst, cnt);
    k_scan1 <<<NBLK_SCAN, 256, 0, stream>>>(cnt, row_ptr, bsum);
    k_scan2 <<<1, 128, 0, stream>>>(bsum);
    k_scan3 <<<(NN + 255) / 256, 256, 0, stream>>>(row_ptr, bsum);
    k_dinv  <<<(NN + 255) / 256, 256, 0, stream>>>(cnt, dinv);
    k_bucket<<<(NE + 255) / 256, 256, 0, stream>>>(src, dst, row_ptr, cursor, bucket);
    k_gather<<<NN * 64 / 256, 256, 0, stream>>>((const float2*)x, dinv, row_ptr, cnt,
                                                bucket, (float2*)out);
    k_gemm  <<<(NN + 127) / 128, 256, 0, stream>>>(out, wt, bias);
}

// Round 11
// 253.933 us; speedup vs baseline: 6.5040x; 1.0848x over previous
//
#include <hip/hip_runtime.h>

#define NN 100000
#define NE 800000
#define NBLK_SCAN 98   // ceil(NN/1024)

typedef __attribute__((ext_vector_type(8))) short bf16x8;
typedef __attribute__((ext_vector_type(4))) float f32x4;

static __device__ __forceinline__ unsigned short f2b(float f) {
    unsigned int u = __builtin_bit_cast(unsigned int, f);
    unsigned int r = (u + 0x7FFFu + ((u >> 16) & 1u)) >> 16;   // RNE
    return (unsigned short)r;
}
static __device__ __forceinline__ float b2f(unsigned int h16) {
    unsigned int u = h16 << 16;
    return __builtin_bit_cast(float, u);
}

// ---- CSR build ----------------------------------------------------------

extern "C" __global__ void k_count(const int* __restrict__ dst, int* __restrict__ cnt) {
    int e = blockIdx.x * 256 + threadIdx.x;
    if (e < NE) atomicAdd(&cnt[dst[e]], 1);
}

extern "C" __global__ void k_scan1(const int* __restrict__ cnt, int* __restrict__ row_ptr,
                                   int* __restrict__ bsum) {
    __shared__ int sh[256];
    int t = threadIdx.x;
    int base = blockIdx.x * 1024 + t * 4;
    int v0 = (base + 0 < NN) ? cnt[base + 0] : 0;
    int v1 = (base + 1 < NN) ? cnt[base + 1] : 0;
    int v2 = (base + 2 < NN) ? cnt[base + 2] : 0;
    int v3 = (base + 3 < NN) ? cnt[base + 3] : 0;
    int tsum = v0 + v1 + v2 + v3;
    sh[t] = tsum;
    __syncthreads();
    int x = tsum;
    for (int off = 1; off < 256; off <<= 1) {
        int y = (t >= off) ? sh[t - off] : 0;
        __syncthreads();
        x += y;
        sh[t] = x;
        __syncthreads();
    }
    int ex = x - tsum;
    if (t == 255) bsum[blockIdx.x] = x;
    if (base + 0 < NN) row_ptr[base + 0] = ex;
    if (base + 1 < NN) row_ptr[base + 1] = ex + v0;
    if (base + 2 < NN) row_ptr[base + 2] = ex + v0 + v1;
    if (base + 3 < NN) row_ptr[base + 3] = ex + v0 + v1 + v2;
}

extern "C" __global__ void k_scan2(int* __restrict__ bsum) {
    __shared__ int sh[128];
    int t = threadIdx.x;
    int v = (t < NBLK_SCAN) ? bsum[t] : 0;
    sh[t] = v;
    __syncthreads();
    int x = v;
    for (int off = 1; off < 128; off <<= 1) {
        int y = (t >= off) ? sh[t - off] : 0;
        __syncthreads();
        x += y;
        sh[t] = x;
        __syncthreads();
    }
    if (t < NBLK_SCAN) bsum[t] = x - v;
}

// row_ptr[i] += bsum-block offset; dinv fused in (k_dinv eliminated)
extern "C" __global__ void k_scan3(int* __restrict__ row_ptr, const int* __restrict__ bsum,
                                   const int* __restrict__ cnt, float* __restrict__ dinv) {
    int i = blockIdx.x * 256 + threadIdx.x;
    if (i < NN) {
        row_ptr[i] += bsum[i >> 10];
        dinv[i] = rsqrtf(1.0f + (float)cnt[i]);
    }
}

// y[s][:] = bf16(x[s][:] * dinv[s])  — halves gather footprint, folds src norm
extern "C" __global__ void k_xprep(const float4* __restrict__ x4,
                                   const float* __restrict__ dinv,
                                   uint2* __restrict__ y) {
    int i = blockIdx.x * 256 + threadIdx.x;   // over NN*32 (exact)
    int row = i >> 5;
    float d = dinv[row];
    float4 v = x4[i];
    uint2 p;
    p.x = (unsigned int)f2b(v.x * d) | ((unsigned int)f2b(v.y * d) << 16);
    p.y = (unsigned int)f2b(v.z * d) | ((unsigned int)f2b(v.w * d) << 16);
    y[i] = p;
}

// bucket[atomic bump of row_ptr[d]] = src; afterwards row_ptr[d] == row end
extern "C" __global__ void k_bucket(const int* __restrict__ src, const int* __restrict__ dst,
                                    int* __restrict__ row_ptr, int* __restrict__ bucket) {
    int e = blockIdx.x * 256 + threadIdx.x;
    if (e >= NE) return;
    int d = dst[e];
    int pos = atomicAdd(&row_ptr[d], 1);
    bucket[pos] = src[e];
}

// ---- W^T -> bf16, pre-swizzled for conflict-free LDS b128 reads ---------
extern "C" __global__ void k_wprep(const float* __restrict__ W, unsigned short* __restrict__ wt) {
    int i = blockIdx.x * 256 + threadIdx.x;   // W row-major [k][n]
    if (i < 128 * 128) {
        int k = i >> 7, n = i & 127;
        int idx = (n * 128 + k) ^ ((n & 7) << 3);
        wt[idx] = f2b(W[i]);
    }
}

// ---- aggregate (gather, bf16 payload) -----------------------------------
// one wave per node, 64 lanes x u32 (2 bf16). acc_raw = y[node] + sum y[s];
// agg = bf16(acc_raw * dinv[node]).
extern "C" __global__ void __launch_bounds__(256) k_gather(
        const unsigned int* __restrict__ y, const float* __restrict__ dinv,
        const int* __restrict__ row_ptr, const int* __restrict__ cnt,
        const int* __restrict__ bucket, unsigned int* __restrict__ aggb) {
    int t = blockIdx.x * 256 + threadIdx.x;
    int node = t >> 6;
    int lane = t & 63;
    float dd = dinv[node];
    unsigned int self = y[node * 64 + lane];
    float ax = b2f(self & 0xFFFFu);
    float ay = b2f(self >> 16);
    int len = cnt[node];
    int j   = row_ptr[node] - len;    // bucket restored start (row_ptr now holds end)
    int end = j + len;
    for (; j + 4 <= end; j += 4) {
        int s0 = bucket[j + 0];
        int s1 = bucket[j + 1];
        int s2 = bucket[j + 2];
        int s3 = bucket[j + 3];
        unsigned int v0 = y[s0 * 64 + lane];
        unsigned int v1 = y[s1 * 64 + lane];
        unsigned int v2 = y[s2 * 64 + lane];
        unsigned int v3 = y[s3 * 64 + lane];
        ax += b2f(v0 & 0xFFFFu) + b2f(v1 & 0xFFFFu) + b2f(v2 & 0xFFFFu) + b2f(v3 & 0xFFFFu);
        ay += b2f(v0 >> 16)     + b2f(v1 >> 16)     + b2f(v2 >> 16)     + b2f(v3 >> 16);
    }
    for (; j < end; j++) {
        unsigned int v = y[bucket[j] * 64 + lane];
        ax += b2f(v & 0xFFFFu);
        ay += b2f(v >> 16);
    }
    unsigned int packed = (unsigned int)f2b(ax * dd) | ((unsigned int)f2b(ay * dd) << 16);
    aggb[node * 64 + lane] = packed;
}

// ---- dense transform: bf16 MFMA, A direct-bf16, out to d_out ------------
extern "C" __global__ void __launch_bounds__(256) k_gemm(
        const unsigned short* __restrict__ aggb, const unsigned int* __restrict__ wt,
        const float* __restrict__ bias, float* __restrict__ out) {
    __shared__ unsigned int wt_lds[8192];   // 32 KB swizzled Wt bf16
    for (int i = threadIdx.x; i < 8192; i += 256)
        wt_lds[i] = wt[i];
    __syncthreads();

    int lane = threadIdx.x & 63;
    int wave = threadIdx.x >> 6;
    int r16  = lane & 15;
    int kg   = lane >> 4;
    long m0  = (long)blockIdx.x * 128 + wave * 32;

    f32x4 acc[2][8];
#pragma unroll
    for (int nt = 0; nt < 8; nt++) {
        float bv = bias[nt * 16 + r16];
        f32x4 iv = {bv, bv, bv, bv};
        acc[0][nt] = iv;
        acc[1][nt] = iv;
    }

#pragma unroll
    for (int ks = 0; ks < 4; ks++) {
        bf16x8 afr[2];
#pragma unroll
        for (int mt = 0; mt < 2; mt++) {
            long r = m0 + mt * 16 + r16;
            if (r >= NN) r = NN - 1;                 // benign clamp; stores guarded
            afr[mt] = *(const bf16x8*)(aggb + r * 128 + ks * 32 + kg * 8);
        }
#pragma unroll
        for (int nt = 0; nt < 8; nt++) {
            int row = nt * 16 + r16;
            int idx = (row * 128 + ks * 32 + kg * 8) ^ ((row & 7) << 3);
            bf16x8 bfr = *(const bf16x8*)((const short*)wt_lds + idx);
            acc[0][nt] = __builtin_amdgcn_mfma_f32_16x16x32_bf16(afr[0], bfr, acc[0][nt], 0, 0, 0);
            acc[1][nt] = __builtin_amdgcn_mfma_f32_16x16x32_bf16(afr[1], bfr, acc[1][nt], 0, 0, 0);
        }
    }

#pragma unroll
    for (int mt = 0; mt < 2; mt++) {
#pragma unroll
        for (int j = 0; j < 4; j++) {
            long r = m0 + mt * 16 + kg * 4 + j;
            if (r < NN) {
#pragma unroll
                for (int nt = 0; nt < 8; nt++)
                    out[r * 128 + nt * 16 + r16] = acc[mt][nt][j];
            }
        }
    }
}

extern "C" void kernel_launch(void* const* d_in, const int* in_sizes, int n_in,
                              void* d_out, int out_size, void* d_ws, size_t ws_size,
                              hipStream_t stream) {
    const float* x    = (const float*)d_in[0];
    const int*   ei   = (const int*)d_in[1];
    const float* W    = (const float*)d_in[2];
    const float* bias = (const float*)d_in[3];
    float* out = (float*)d_out;

    const int* src = ei;
    const int* dst = ei + NE;

    // workspace (u32 elems): cnt NN | row_ptr NN | dinv NN | bsum 128 | bucket NE
    //                        | wt 8192 | aggb NN*64
    int*   cnt     = (int*)d_ws;
    int*   row_ptr = cnt + NN;
    float* dinv    = (float*)(row_ptr + NN);
    int*   bsum    = (int*)(dinv + NN);
    int*   bucket  = bsum + 128;
    unsigned int* wt   = (unsigned int*)(bucket + NE);
    unsigned int* aggb = wt + 8192;                  // NN*64 u32 = 25.6 MB
    // y (bf16 x*dinv) lives in d_out's front half (25.6 MB of 51.2 MB);
    // consumed by k_gather, then k_gemm overwrites all of d_out.
    uint2* y = (uint2*)d_out;

    hipMemsetAsync(cnt, 0, (size_t)NN * sizeof(int), stream);

    k_wprep <<<64, 256, 0, stream>>>(W, (unsigned short*)wt);
    k_count <<<(NE + 255) / 256, 256, 0, stream>>>(dst, cnt);
    k_scan1 <<<NBLK_SCAN, 256, 0, stream>>>(cnt, row_ptr, bsum);
    k_scan2 <<<1, 128, 0, stream>>>(bsum);
    k_scan3 <<<(NN + 255) / 256, 256, 0, stream>>>(row_ptr, bsum, cnt, dinv);
    k_xprep <<<NN * 32 / 256, 256, 0, stream>>>((const float4*)x, dinv, y);
    k_bucket<<<(NE + 255) / 256, 256, 0, stream>>>(src, dst, row_ptr, bucket);
    k_gather<<<NN * 64 / 256, 256, 0, stream>>>((const unsigned int*)y, dinv, row_ptr, cnt,
                                                bucket, aggb);
    k_gemm  <<<(NN + 127) / 128, 256, 0, stream>>>((const unsigned short*)aggb, wt, bias, out);
}

// Round 12
// 209.509 us; speedup vs baseline: 7.8831x; 1.2120x over previous
//
#include <hip/hip_runtime.h>

#define NN 100000
#define NE 800000
#define CAP 24            // fixed bucket slots per node (P(deg>24)~1e-6)
#define SHN 12500         // nodes per shard (8 shards exactly cover NN)
#define CH 8192           // edges per chunk
#define NC ((NE + CH - 1) / CH)   // 98 chunks
#define MAXOFL 32768

typedef __attribute__((ext_vector_type(8))) short bf16x8;
typedef __attribute__((ext_vector_type(4))) float f32x4;

static __device__ __forceinline__ unsigned short f2b(float f) {
    unsigned int u = __builtin_bit_cast(unsigned int, f);
    unsigned int r = (u + 0x7FFFu + ((u >> 16) & 1u)) >> 16;   // RNE
    return (unsigned short)r;
}
static __device__ __forceinline__ float b2f(unsigned int h16) {
    unsigned int u = h16 << 16;
    return __builtin_bit_cast(float, u);
}

// ---- single-pass sharded count+bucket -----------------------------------
// block = (chunk c, shard s); processes edges of chunk c whose dst lies in
// shard s's node range. With round-robin block->XCD dispatch, all writes to
// cnt/bucket of shard s stay on one XCD's L2 (perf heuristic only;
// correctness holds for any mapping: each (chunk,shard) pair runs once).
extern "C" __global__ void __launch_bounds__(256) k_bucket1(
        const int* __restrict__ src, const int* __restrict__ dst,
        int* __restrict__ cnt, int* __restrict__ bucket,
        int* __restrict__ ofl, int* __restrict__ oflcnt) {
    int s = blockIdx.x & 7;
    int c = blockIdx.x >> 3;
    int e0 = c * CH;
    int e1 = e0 + CH; if (e1 > NE) e1 = NE;
    int lo = s * SHN, hi = lo + SHN;
    for (int e = e0 + threadIdx.x; e < e1; e += 256) {
        int d = dst[e];
        if (d >= lo && d < hi) {
            int pos = atomicAdd(&cnt[d], 1);
            if (pos < CAP) {
                bucket[d * CAP + pos] = src[e];
            } else {
                int o = atomicAdd(oflcnt, 1);
                if (o < MAXOFL) { ofl[2 * o] = d; ofl[2 * o + 1] = src[e]; }
            }
        }
    }
}

// y[s][:] = bf16(x[s][:] * rsqrt(1+deg(s)))
extern "C" __global__ void k_xprep(const float4* __restrict__ x4,
                                   const int* __restrict__ cnt,
                                   uint2* __restrict__ y) {
    int i = blockIdx.x * 256 + threadIdx.x;   // over NN*32 (exact)
    int row = i >> 5;
    float d = rsqrtf(1.0f + (float)cnt[row]);
    float4 v = x4[i];
    uint2 p;
    p.x = (unsigned int)f2b(v.x * d) | ((unsigned int)f2b(v.y * d) << 16);
    p.y = (unsigned int)f2b(v.z * d) | ((unsigned int)f2b(v.w * d) << 16);
    y[i] = p;
}

// ---- W^T -> bf16, pre-swizzled for conflict-free LDS b128 reads ---------
extern "C" __global__ void k_wprep(const float* __restrict__ W, unsigned short* __restrict__ wt) {
    int i = blockIdx.x * 256 + threadIdx.x;   // W row-major [k][n]
    if (i < 128 * 128) {
        int k = i >> 7, n = i & 127;
        int idx = (n * 128 + k) ^ ((n & 7) << 3);
        wt[idx] = f2b(W[i]);
    }
}

// ---- aggregate (gather, bf16 payload, fixed-stride bucket) --------------
extern "C" __global__ void __launch_bounds__(256) k_gather(
        const unsigned int* __restrict__ y, const int* __restrict__ cnt,
        const int* __restrict__ bucket, unsigned int* __restrict__ aggb) {
    int t = blockIdx.x * 256 + threadIdx.x;
    int node = t >> 6;
    int lane = t & 63;
    int len = cnt[node];
    float dd = rsqrtf(1.0f + (float)len);
    unsigned int self = y[node * 64 + lane];
    float ax = b2f(self & 0xFFFFu);
    float ay = b2f(self >> 16);
    int lim = len < CAP ? len : CAP;
    int base = node * CAP;
    int j = 0;
    for (; j + 4 <= lim; j += 4) {
        int s0 = bucket[base + j + 0];
        int s1 = bucket[base + j + 1];
        int s2 = bucket[base + j + 2];
        int s3 = bucket[base + j + 3];
        unsigned int v0 = y[s0 * 64 + lane];
        unsigned int v1 = y[s1 * 64 + lane];
        unsigned int v2 = y[s2 * 64 + lane];
        unsigned int v3 = y[s3 * 64 + lane];
        ax += b2f(v0 & 0xFFFFu) + b2f(v1 & 0xFFFFu) + b2f(v2 & 0xFFFFu) + b2f(v3 & 0xFFFFu);
        ay += b2f(v0 >> 16)     + b2f(v1 >> 16)     + b2f(v2 >> 16)     + b2f(v3 >> 16);
    }
    for (; j < lim; j++) {
        unsigned int v = y[bucket[base + j] * 64 + lane];
        ax += b2f(v & 0xFFFFu);
        ay += b2f(v >> 16);
    }
    unsigned int packed = (unsigned int)f2b(ax * dd) | ((unsigned int)f2b(ay * dd) << 16);
    aggb[node * 64 + lane] = packed;
}

// ---- overflow fixup (deg > CAP; expected count ~0, safety path) ---------
extern "C" __global__ void __launch_bounds__(256) k_ofl(
        const unsigned int* __restrict__ y, const int* __restrict__ cnt,
        const int* __restrict__ ofl, const int* __restrict__ oflcnt,
        unsigned int* __restrict__ aggb) {
    int wid  = blockIdx.x * 4 + (threadIdx.x >> 6);
    int lane = threadIdx.x & 63;
    int n = *oflcnt; if (n > MAXOFL) n = MAXOFL;
    for (int i = wid; i < n; i += 512) {
        int d  = ofl[2 * i];
        int sv = ofl[2 * i + 1];
        float dd = rsqrtf(1.0f + (float)cnt[d]);
        unsigned int v = y[sv * 64 + lane];
        float cx = b2f(v & 0xFFFFu) * dd;
        float cy = b2f(v >> 16) * dd;
        unsigned int* p = &aggb[d * 64 + lane];
        unsigned int old = *p, assumed;
        do {
            assumed = old;
            float nx = b2f(assumed & 0xFFFFu) + cx;
            float ny = b2f(assumed >> 16) + cy;
            unsigned int nw = (unsigned int)f2b(nx) | ((unsigned int)f2b(ny) << 16);
            old = atomicCAS(p, assumed, nw);
        } while (old != assumed);
    }
}

// ---- dense transform: bf16 MFMA -----------------------------------------
extern "C" __global__ void __launch_bounds__(256) k_gemm(
        const unsigned short* __restrict__ aggb, const unsigned int* __restrict__ wt,
        const float* __restrict__ bias, float* __restrict__ out) {
    __shared__ unsigned int wt_lds[8192];   // 32 KB swizzled Wt bf16
    for (int i = threadIdx.x; i < 8192; i += 256)
        wt_lds[i] = wt[i];
    __syncthreads();

    int lane = threadIdx.x & 63;
    int wave = threadIdx.x >> 6;
    int r16  = lane & 15;
    int kg   = lane >> 4;
    long m0  = (long)blockIdx.x * 128 + wave * 32;

    f32x4 acc[2][8];
#pragma unroll
    for (int nt = 0; nt < 8; nt++) {
        float bv = bias[nt * 16 + r16];
        f32x4 iv = {bv, bv, bv, bv};
        acc[0][nt] = iv;
        acc[1][nt] = iv;
    }

#pragma unroll
    for (int ks = 0; ks < 4; ks++) {
        bf16x8 afr[2];
#pragma unroll
        for (int mt = 0; mt < 2; mt++) {
            long r = m0 + mt * 16 + r16;
            if (r >= NN) r = NN - 1;                 // benign clamp; stores guarded
            afr[mt] = *(const bf16x8*)(aggb + r * 128 + ks * 32 + kg * 8);
        }
#pragma unroll
        for (int nt = 0; nt < 8; nt++) {
            int row = nt * 16 + r16;
            int idx = (row * 128 + ks * 32 + kg * 8) ^ ((row & 7) << 3);
            bf16x8 bfr = *(const bf16x8*)((const short*)wt_lds + idx);
            acc[0][nt] = __builtin_amdgcn_mfma_f32_16x16x32_bf16(afr[0], bfr, acc[0][nt], 0, 0, 0);
            acc[1][nt] = __builtin_amdgcn_mfma_f32_16x16x32_bf16(afr[1], bfr, acc[1][nt], 0, 0, 0);
        }
    }

#pragma unroll
    for (int mt = 0; mt < 2; mt++) {
#pragma unroll
        for (int j = 0; j < 4; j++) {
            long r = m0 + mt * 16 + kg * 4 + j;
            if (r < NN) {
#pragma unroll
                for (int nt = 0; nt < 8; nt++)
                    out[r * 128 + nt * 16 + r16] = acc[mt][nt][j];
            }
        }
    }
}

extern "C" void kernel_launch(void* const* d_in, const int* in_sizes, int n_in,
                              void* d_out, int out_size, void* d_ws, size_t ws_size,
                              hipStream_t stream) {
    const float* x    = (const float*)d_in[0];
    const int*   ei   = (const int*)d_in[1];
    const float* W    = (const float*)d_in[2];
    const float* bias = (const float*)d_in[3];
    float* out = (float*)d_out;

    const int* src = ei;
    const int* dst = ei + NE;

    // ws layout (u32): cnt NN | oflcnt 1 (+63 pad) | bucket NN*CAP | ofl 2*MAXOFL
    //                  | wt 8192 | aggb NN*64      (~36 MB total)
    int*   cnt    = (int*)d_ws;
    int*   oflcnt = cnt + NN;
    int*   bucket = oflcnt + 64;
    int*   ofl    = bucket + (size_t)NN * CAP;
    unsigned int* wt   = (unsigned int*)(ofl + 2 * MAXOFL);
    unsigned int* aggb = wt + 8192;                  // NN*64 u32 = 25.6 MB
    // y (bf16 x*dinv) lives in d_out's front half; k_gemm later overwrites d_out.
    uint2* y = (uint2*)d_out;

    hipMemsetAsync(cnt, 0, (size_t)(NN + 64) * sizeof(int), stream);

    k_wprep  <<<64, 256, 0, stream>>>(W, (unsigned short*)wt);
    k_bucket1<<<NC * 8, 256, 0, stream>>>(src, dst, cnt, bucket, ofl, oflcnt);
    k_xprep  <<<NN * 32 / 256, 256, 0, stream>>>((const float4*)x, cnt, y);
    k_gather <<<NN * 64 / 256, 256, 0, stream>>>((const unsigned int*)y, cnt, bucket, aggb);
    k_ofl    <<<128, 256, 0, stream>>>((const unsigned int*)y, cnt, ofl, oflcnt, aggb);
    k_gemm   <<<(NN + 127) / 128, 256, 0, stream>>>((const unsigned short*)aggb, wt, bias, out);
}